// Round 4
// baseline (701.578 us; speedup 1.0000x reference)
//
#include <hip/hip_runtime.h>
#include <math.h>

#define B_ 16
#define LC_ 512
#define LP_ 4096
#define H_ 128
#define HH_ (H_*H_)

typedef __attribute__((ext_vector_type(8))) short bf16x8;
typedef __attribute__((ext_vector_type(4))) float f32x4;

__device__ __forceinline__ unsigned short f2bf(float f) {
    union { float f; unsigned u; } v; v.f = f;
    unsigned r = (v.u + 0x7FFFu + ((v.u >> 16) & 1u)) >> 16;
    return (unsigned short)r;
}

__device__ __forceinline__ bf16x8 ldfrag(const short* Vt, int h, int k) {
    const unsigned long long* p = (const unsigned long long*)(Vt + h * 68 + k);
    union { bf16x8 v; unsigned long long q[2]; } u;
    u.q[0] = p[0]; u.q[1] = p[1];
    return u.v;
}

// stage 64 k-rows x 128 h of fp32 (optionally masked per-row) into h-major bf16
// LDS tile Vt[128][68]. 256 threads: t&31 -> h-group of 4, t>>5 -> k-quad.
__device__ __forceinline__ void stage64(const float* __restrict__ src,
                                        const int* __restrict__ maskrow,
                                        short* __restrict__ dst, int t) {
    const int m = t & 31, kq = t >> 5;
#pragma unroll
    for (int p = 0; p < 2; ++p) {
        const int kc = p * 32 + kq * 4;
        const float4* s4 = (const float4*)(src + (size_t)kc * H_);
        float4 r0 = s4[0 * 32 + m];
        float4 r1 = s4[1 * 32 + m];
        float4 r2 = s4[2 * 32 + m];
        float4 r3 = s4[3 * 32 + m];
        if (maskrow) {
            float m0 = (float)maskrow[kc + 0], m1 = (float)maskrow[kc + 1];
            float m2 = (float)maskrow[kc + 2], m3 = (float)maskrow[kc + 3];
            r0.x *= m0; r0.y *= m0; r0.z *= m0; r0.w *= m0;
            r1.x *= m1; r1.y *= m1; r1.z *= m1; r1.w *= m1;
            r2.x *= m2; r2.y *= m2; r2.z *= m2; r2.w *= m2;
            r3.x *= m3; r3.y *= m3; r3.z *= m3; r3.w *= m3;
        }
        float c0[4] = {r0.x, r0.y, r0.z, r0.w};
        float c1[4] = {r1.x, r1.y, r1.z, r1.w};
        float c2[4] = {r2.x, r2.y, r2.z, r2.w};
        float c3[4] = {r3.x, r3.y, r3.z, r3.w};
#pragma unroll
        for (int i = 0; i < 4; ++i) {
            unsigned long long v = (unsigned long long)f2bf(c0[i])
                                 | ((unsigned long long)f2bf(c1[i]) << 16)
                                 | ((unsigned long long)f2bf(c2[i]) << 32)
                                 | ((unsigned long long)f2bf(c3[i]) << 48);
            *(unsigned long long*)(dst + (size_t)(4 * m + i) * 68 + kc) = v;
        }
    }
}

// part[(slice*B+b)] (128x128 fp32) = sum over this slice's k of
//   (mask[k]*Xl[k,:])^T (outer) Yr[k,:]   via bf16 MFMA, fp32 accum.
// SAME=true: Yr==Xl (symmetric, mask folded once since mask is binary).
template<bool SAME>
__global__ __launch_bounds__(256) void syrk_mfma_k(const float* __restrict__ Xl,
                                                   const float* __restrict__ Yr,
                                                   const int* __restrict__ mask,
                                                   float* __restrict__ part,
                                                   int Kb, int rowsPerSlice) {
    extern __shared__ short smem[];
    short* Xt = smem;
    short* Yt = SAME ? smem : (smem + 128 * 68);
    const int t = threadIdx.x;
    const int b = blockIdx.y, slice = blockIdx.x;
    const int l = t & 63, w = t >> 6;
    const int qi = (w >> 1) * 64, qj = (w & 1) * 64;
    const int lm = l & 15, lk = (l >> 4) * 8, lr = (l >> 4) * 4;

    f32x4 acc[4][4] = {};
    const int chunks = rowsPerSlice >> 6;
    const size_t boff = (size_t)b * Kb;

    for (int c = 0; c < chunks; ++c) {
        const int kbase = slice * rowsPerSlice + c * 64;
        stage64(Xl + (boff + kbase) * H_, mask + boff + kbase, Xt, t);
        if (!SAME) stage64(Yr + (boff + kbase) * H_, nullptr, Yt, t);
        __syncthreads();
#pragma unroll
        for (int ks = 0; ks < 64; ks += 32) {
            bf16x8 af[4], bfr[4];
#pragma unroll
            for (int it = 0; it < 4; ++it) af[it] = ldfrag(Xt, qi + it * 16 + lm, ks + lk);
#pragma unroll
            for (int jt = 0; jt < 4; ++jt) bfr[jt] = ldfrag(Yt, qj + jt * 16 + lm, ks + lk);
#pragma unroll
            for (int it = 0; it < 4; ++it)
#pragma unroll
                for (int jt = 0; jt < 4; ++jt)
                    acc[it][jt] = __builtin_amdgcn_mfma_f32_16x16x32_bf16(
                        af[it], bfr[jt], acc[it][jt], 0, 0, 0);
        }
        __syncthreads();
    }

    float* pb = part + ((size_t)slice * B_ + b) * HH_;
#pragma unroll
    for (int it = 0; it < 4; ++it)
#pragma unroll
        for (int jt = 0; jt < 4; ++jt)
#pragma unroll
            for (int r = 0; r < 4; ++r)
                pb[(size_t)(qi + it * 16 + lr + r) * H_ + qj + jt * 16 + lm] = acc[it][jt][r];
}

// out[idx] = sum_s part[s][idx], idx over B*HH/4 float4s
__global__ __launch_bounds__(256) void reduce_k(const float4* __restrict__ part,
                                                float4* __restrict__ out, int slices) {
    const int idx = blockIdx.x * 256 + threadIdx.x;
    float4 a = part[idx];
    for (int s = 1; s < slices; ++s) {
        float4 v = part[(size_t)s * (B_ * HH_ / 4) + idx];
        a.x += v.x; a.y += v.y; a.z += v.z; a.w += v.w;
    }
    out[idx] = a;
}

// ---------------- GEMM128: Y[r][0..127] = act(X[r][:]@W + bias) ----------------
template<bool TANH>
__global__ __launch_bounds__(256) void gemm128_k(const float* __restrict__ X,
                                                 const float* __restrict__ W,
                                                 const float* __restrict__ bias,
                                                 float* __restrict__ Y) {
    __shared__ float Ws[HH_];
    __shared__ float Xs[128 * 32];  // transposed [k][r]
    const int t = threadIdx.x;
    const long row0 = (long)blockIdx.x * 32;

    const float4* W4 = (const float4*)W;
    float4* Ws4 = (float4*)Ws;
#pragma unroll
    for (int j = 0; j < 16; ++j) Ws4[j * 256 + t] = W4[j * 256 + t];

    const float4* X4 = (const float4*)(X + row0 * H_);
#pragma unroll
    for (int j = 0; j < 4; ++j) {
        int idx = j * 256 + t;
        int r = idx >> 5, k4 = idx & 31;
        float4 v = X4[idx];
        Xs[(k4 * 4 + 0) * 32 + r] = v.x;
        Xs[(k4 * 4 + 1) * 32 + r] = v.y;
        Xs[(k4 * 4 + 2) * 32 + r] = v.z;
        Xs[(k4 * 4 + 3) * 32 + r] = v.w;
    }
    __syncthreads();

    const int cg = t & 31;
    const int rg = t >> 5;
    float acc[4][4] = {};
#pragma unroll 4
    for (int k = 0; k < 128; ++k) {
        float4 xv = ((const float4*)Xs)[k * 8 + rg];
        float4 wv = ((const float4*)Ws)[k * 32 + cg];
        float xr[4] = {xv.x, xv.y, xv.z, xv.w};
        float wr[4] = {wv.x, wv.y, wv.z, wv.w};
#pragma unroll
        for (int a = 0; a < 4; ++a)
#pragma unroll
            for (int c = 0; c < 4; ++c)
                acc[a][c] = fmaf(xr[a], wr[c], acc[a][c]);
    }

    float bv[4] = {0.f, 0.f, 0.f, 0.f};
    if (bias) {
        float4 bq = ((const float4*)bias)[cg];
        bv[0] = bq.x; bv[1] = bq.y; bv[2] = bq.z; bv[3] = bq.w;
    }
#pragma unroll
    for (int a = 0; a < 4; ++a) {
        float v0 = acc[a][0] + bv[0], v1 = acc[a][1] + bv[1];
        float v2 = acc[a][2] + bv[2], v3 = acc[a][3] + bv[3];
        if (TANH) { v0 = tanhf(v0); v1 = tanhf(v1); v2 = tanhf(v2); v3 = tanhf(v3); }
        float4 o; o.x = v0; o.y = v1; o.z = v2; o.w = v3;
        ((float4*)(Y + (row0 + rg * 4 + a) * H_))[cg] = o;
    }
}

// ------------- ctx GEMM: Y[b,r,:] = mask[b,r] * (X[b,r,:] @ Mw[b]) -------------
__global__ __launch_bounds__(256) void ctx_gemm_k(const float* __restrict__ Xall,
                                                  const float* __restrict__ Mall,
                                                  const int* __restrict__ mask,
                                                  float* __restrict__ Y, int rowsPerB) {
    __shared__ float Ws[HH_];
    __shared__ float Xs[128 * 32];
    const int t = threadIdx.x;
    const int b = blockIdx.y;
    const long row0 = (long)b * rowsPerB + (long)blockIdx.x * 32;
    const float* W = Mall + (size_t)b * HH_;

    const float4* W4 = (const float4*)W;
    float4* Ws4 = (float4*)Ws;
#pragma unroll
    for (int j = 0; j < 16; ++j) Ws4[j * 256 + t] = W4[j * 256 + t];

    const float4* X4 = (const float4*)(Xall + row0 * H_);
#pragma unroll
    for (int j = 0; j < 4; ++j) {
        int idx = j * 256 + t;
        int r = idx >> 5, k4 = idx & 31;
        float4 v = X4[idx];
        Xs[(k4 * 4 + 0) * 32 + r] = v.x;
        Xs[(k4 * 4 + 1) * 32 + r] = v.y;
        Xs[(k4 * 4 + 2) * 32 + r] = v.z;
        Xs[(k4 * 4 + 3) * 32 + r] = v.w;
    }
    __syncthreads();

    const int cg = t & 31;
    const int rg = t >> 5;
    float acc[4][4] = {};
#pragma unroll 4
    for (int k = 0; k < 128; ++k) {
        float4 xv = ((const float4*)Xs)[k * 8 + rg];
        float4 wv = ((const float4*)Ws)[k * 32 + cg];
        float xr[4] = {xv.x, xv.y, xv.z, xv.w};
        float wr[4] = {wv.x, wv.y, wv.z, wv.w};
#pragma unroll
        for (int a = 0; a < 4; ++a)
#pragma unroll
            for (int c = 0; c < 4; ++c)
                acc[a][c] = fmaf(xr[a], wr[c], acc[a][c]);
    }
#pragma unroll
    for (int a = 0; a < 4; ++a) {
        long row = row0 + rg * 4 + a;
        float sc = (float)mask[row];
        float4 o;
        o.x = acc[a][0] * sc; o.y = acc[a][1] * sc;
        o.z = acc[a][2] * sc; o.w = acc[a][3] * sc;
        ((float4*)(Y + row * H_))[cg] = o;
    }
}

// ---- vc[b] = M[b] @ Wac ; vp[b] = N[b] @ Wap ----
__global__ void mv_k(const float* __restrict__ M, const float* __restrict__ N,
                     const float* __restrict__ Wac, const float* __restrict__ Wap,
                     float* __restrict__ vc, float* __restrict__ vp) {
    int b = blockIdx.x, t = threadIdx.x;
    const float* mat = (t < 128) ? (M + (size_t)b * HH_ + (size_t)t * H_)
                                 : (N + (size_t)b * HH_ + (size_t)(t - 128) * H_);
    const float* w = (t < 128) ? Wac : Wap;
    float acc = 0.f;
#pragma unroll 8
    for (int h = 0; h < H_; ++h) acc = fmaf(mat[h], w[h], acc);
    if (t < 128) vc[b * H_ + t] = acc;
    else         vp[b * H_ + (t - 128)] = acc;
}

// ---- logits[b,r] = mask[b,r] * (feat[b,r,:] . v[b]) + bias ----
__global__ void logits_k(const float* __restrict__ feat, const int* __restrict__ mask,
                         const float* __restrict__ v, const float* __restrict__ biasPtr,
                         float* __restrict__ out, int n) {
    int idx = blockIdx.x * blockDim.x + threadIdx.x;
    int b = idx / n;
    const float4* r4 = (const float4*)(feat + (size_t)idx * H_);
    const float4* v4 = (const float4*)(v + (size_t)b * H_);
    float acc = 0.f;
#pragma unroll
    for (int h4 = 0; h4 < 32; ++h4) {
        float4 a = r4[h4], c = v4[h4];
        acc = fmaf(a.x, c.x, acc); acc = fmaf(a.y, c.y, acc);
        acc = fmaf(a.z, c.z, acc); acc = fmaf(a.w, c.w, acc);
    }
    out[idx] = (float)mask[idx] * acc + biasPtr[0];
}

// ---- masked softmax, faithful: max over ALL, exp*mask, denom + 1e-6 ----
__global__ __launch_bounds__(256) void softmax_k(const float* __restrict__ logits,
                                                 const int* __restrict__ mask,
                                                 float* __restrict__ w, int n) {
    int b = blockIdx.x, t = threadIdx.x;
    const float* l = logits + (size_t)b * n;
    const int* mk = mask + (size_t)b * n;
    float* ww = w + (size_t)b * n;
    __shared__ float Es[4096];
    __shared__ float red[4];

    float mx = -1e30f;
    for (int q = t; q < n; q += 256) mx = fmaxf(mx, l[q]);
#pragma unroll
    for (int o = 32; o > 0; o >>= 1) mx = fmaxf(mx, __shfl_down(mx, o, 64));
    if ((t & 63) == 0) red[t >> 6] = mx;
    __syncthreads();
    float m = fmaxf(fmaxf(red[0], red[1]), fmaxf(red[2], red[3]));
    __syncthreads();

    float s = 0.f;
    for (int q = t; q < n; q += 256) {
        float e = __expf(l[q] - m) * (float)mk[q];
        Es[q] = e;
        s += e;
    }
#pragma unroll
    for (int o = 32; o > 0; o >>= 1) s += __shfl_down(s, o, 64);
    if ((t & 63) == 0) red[t >> 6] = s;
    __syncthreads();
    float denom = red[0] + red[1] + red[2] + red[3] + 1e-6f;
    for (int q = t; q < n; q += 256) ww[q] = Es[q] / denom;
}

// ---- pooled[b,h] += sum_{q in chunk} proj[b,q,h] * w[b,q] ----
__global__ void pool_k(const float* __restrict__ proj, const float* __restrict__ w,
                       float* __restrict__ out, int n, int chunk) {
    int b = blockIdx.x, h = threadIdx.x;
    int q0 = blockIdx.y * chunk;
    const float* pb = proj + ((size_t)b * n + q0) * H_;
    const float* wb = w + (size_t)b * n + q0;
    float acc = 0.f;
#pragma unroll 4
    for (int q = 0; q < chunk; ++q) acc = fmaf(pb[(size_t)q * H_ + h], wb[q], acc);
    atomicAdd(&out[b * H_ + h], acc);
}

// ---- final[b,h] = concat(pooled[0..2])[b,:] @ Wcomb + bcomb ----
__global__ void final_k(const float* __restrict__ pooled, const float* __restrict__ Wcomb,
                        const float* __restrict__ bcomb, float* __restrict__ out) {
    int b = blockIdx.x, h = threadIdx.x;
    float acc = bcomb[h];
#pragma unroll 4
    for (int j = 0; j < 3 * H_; ++j) {
        int lay = j >> 7, hh = j & 127;
        acc = fmaf(pooled[((size_t)lay * B_ + b) * H_ + hh], Wcomb[j * H_ + h], acc);
    }
    out[b * H_ + h] = acc;
}

extern "C" void kernel_launch(void* const* d_in, const int* in_sizes, int n_in,
                              void* d_out, int out_size, void* d_ws, size_t ws_size,
                              hipStream_t stream) {
    const float* comp_feat = (const float*)d_in[0];
    const int*   comp_mask = (const int*)d_in[1];
    const float* prot_feat = (const float*)d_in[2];
    const int*   prot_mask = (const int*)d_in[3];
    const float* Wc      = (const float*)d_in[4];
    const float* bc      = (const float*)d_in[5];
    const float* Wp      = (const float*)d_in[6];
    const float* bp      = (const float*)d_in[7];
    const float* Wbl     = (const float*)d_in[8];
    const float* Wac     = (const float*)d_in[9];
    const float* bac     = (const float*)d_in[10];
    const float* Wap     = (const float*)d_in[11];
    const float* bap     = (const float*)d_in[12];
    const float* Wcomb_c = (const float*)d_in[13];
    const float* bcomb_c = (const float*)d_in[14];
    const float* Wcomb_p = (const float*)d_in[15];
    const float* bcomb_p = (const float*)d_in[16];

    float* ws = (float*)d_ws;
    float* prot_proj = ws;                                   // 16*4096*128
    float* comp_proj = prot_proj + (size_t)B_ * LP_ * H_;    // 16*512*128
    float* comp_bil  = comp_proj + (size_t)B_ * LC_ * H_;    // 16*512*128
    float* Mbuf = comp_bil + (size_t)B_ * LC_ * H_;          // 16*128*128
    float* Nbuf = Mbuf + (size_t)B_ * HH_;                   // 16*128*128
    float* vc   = Nbuf + (size_t)B_ * HH_;                   // 16*128
    float* vp   = vc + B_ * H_;
    float* logc = vp + B_ * H_;                              // 16*512
    float* logp = logc + B_ * LC_;                           // 16*4096
    float* cw   = logp + B_ * LP_;                           // 16*512
    float* pw   = cw + B_ * LC_;                             // 16*4096
    float* cp   = pw + B_ * LP_;                             // 3*16*128
    float* pp   = cp + 3 * B_ * H_;                          // 3*16*128

    float* out_cf = (float*)d_out;
    float* out_pf = out_cf + B_ * H_;
    float* out_cc = out_pf + B_ * H_;
    float* out_pc = out_cc + (size_t)B_ * LC_ * H_;

    // out_pc (16*4096*128 fp32 = 33.5MB) doubles as the syrk partial buffer;
    // it is only written as real output at the very end of layer 2.
    float* part = out_pc;

    const int SLICES_P = 32;  // 4096/32 = 128 rows/slice -> 33.5MB partials (fits exactly)
    const int SLICES_C = 8;   // 512/8  = 64 rows/slice  -> 8.4MB partials

    for (int i = 0; i < 3; ++i) {
        hipMemsetAsync(cp + (size_t)i * B_ * H_, 0, (size_t)B_ * H_ * sizeof(float), stream);
        hipMemsetAsync(pp + (size_t)i * B_ * H_, 0, (size_t)B_ * H_ * sizeof(float), stream);

        gemm128_k<true><<<dim3(B_ * LP_ / 32), 256, 0, stream>>>(
            prot_feat, Wp + (size_t)i * HH_, bp + i * H_, prot_proj);
        gemm128_k<true><<<dim3(B_ * LC_ / 32), 256, 0, stream>>>(
            comp_feat, Wc + (size_t)i * HH_, bc + i * H_, comp_proj);
        gemm128_k<false><<<dim3(B_ * LC_ / 32), 256, 0, stream>>>(
            comp_proj, Wbl + (size_t)i * HH_, nullptr, comp_bil);

        // M = prot_proj^T diag(pm) prot_proj   (mask folded once: pm binary)
        syrk_mfma_k<true><<<dim3(SLICES_P, B_), 256, 128 * 68 * sizeof(short), stream>>>(
            prot_proj, prot_proj, prot_mask, part, LP_, LP_ / SLICES_P);
        reduce_k<<<dim3(B_ * HH_ / 4 / 256), 256, 0, stream>>>(
            (const float4*)part, (float4*)Mbuf, SLICES_P);

        // N = comp_bil^T diag(cm) comp_proj
        syrk_mfma_k<false><<<dim3(SLICES_C, B_), 256, 2 * 128 * 68 * sizeof(short), stream>>>(
            comp_bil, comp_proj, comp_mask, part, LC_, LC_ / SLICES_C);
        reduce_k<<<dim3(B_ * HH_ / 4 / 256), 256, 0, stream>>>(
            (const float4*)part, (float4*)Nbuf, SLICES_C);

        mv_k<<<dim3(B_), 256, 0, stream>>>(Mbuf, Nbuf, Wac + i * H_, Wap + i * H_, vc, vp);

        logits_k<<<dim3(B_ * LC_ / 256), 256, 0, stream>>>(comp_bil, comp_mask, vc, bac + i, logc, LC_);
        logits_k<<<dim3(B_ * LP_ / 256), 256, 0, stream>>>(prot_proj, prot_mask, vp, bap + i, logp, LP_);

        softmax_k<<<dim3(B_), 256, 0, stream>>>(logc, comp_mask, cw, LC_);
        softmax_k<<<dim3(B_), 256, 0, stream>>>(logp, prot_mask, pw, LP_);

        pool_k<<<dim3(B_, 2), 128, 0, stream>>>(comp_proj, cw, cp + (size_t)i * B_ * H_, LC_, 256);
        pool_k<<<dim3(B_, 8), 128, 0, stream>>>(prot_proj, pw, pp + (size_t)i * B_ * H_, LP_, 512);

        if (i == 2) {
            ctx_gemm_k<<<dim3(LC_ / 32, B_), 256, 0, stream>>>(comp_bil, Mbuf, comp_mask, out_cc, LC_);
            ctx_gemm_k<<<dim3(LP_ / 32, B_), 256, 0, stream>>>(prot_proj, Nbuf, prot_mask, out_pc, LP_);
        }
    }

    final_k<<<dim3(B_), 128, 0, stream>>>(cp, Wcomb_c, bcomb_c, out_cf);
    final_k<<<dim3(B_), 128, 0, stream>>>(pp, Wcomb_p, bcomb_p, out_pf);
}

// Round 5
// 522.041 us; speedup vs baseline: 1.3439x; 1.3439x over previous
//
#include <hip/hip_runtime.h>
#include <math.h>

#define B_ 16
#define LC_ 512
#define LP_ 4096
#define H_ 128
#define HH_ (H_*H_)

typedef unsigned long long u64t;
typedef unsigned short u16t;
typedef __attribute__((ext_vector_type(8))) short bf16x8;
typedef __attribute__((ext_vector_type(4))) float f32x4;

__device__ __forceinline__ u16t f2bf(float f) {
    union { float f; unsigned u; } v; v.f = f;
    unsigned r = (v.u + 0x7FFFu + ((v.u >> 16) & 1u)) >> 16;
    return (u16t)r;
}
__device__ __forceinline__ float bf2f(u16t s) {
    union { unsigned u; float f; } v; v.u = ((unsigned)s) << 16; return v.f;
}
__device__ __forceinline__ float bflo(unsigned u) {
    union { unsigned u; float f; } v; v.u = u << 16; return v.f;
}
__device__ __forceinline__ float bfhi(unsigned u) {
    union { unsigned u; float f; } v; v.u = u & 0xffff0000u; return v.f;
}
__device__ __forceinline__ float ftanh(float x) {
    x = fminf(15.f, fmaxf(-15.f, x));
    float t = __expf(2.f * x);
    return (t - 1.f) / (t + 1.f);
}
// 8 contiguous bf16 (as shorts) at row r, col k of an LDS tile with given stride
__device__ __forceinline__ bf16x8 ldfragS(const short* base, int r, int k, int stride) {
    const u64t* p = (const u64t*)(base + (size_t)r * stride + k);
    union { bf16x8 v; u64t q[2]; } u;
    u.q[0] = p[0]; u.q[1] = p[1];
    return u.v;
}

// fp32 W rows [64 k][128 n] -> transposed bf16 hi/lo tiles [64 n][68], cols ncol0..+63.
// 256 threads: m = t&15 -> n-group of 4, kq = t>>4 -> k-quad.
__device__ __forceinline__ void stage64_hl(const float* __restrict__ src, int ncol0,
                                           short* __restrict__ hi, short* __restrict__ lo,
                                           int t) {
    const int m = t & 15, kq = t >> 4;
    const int kc = kq * 4;
    float c[4][4];
#pragma unroll
    for (int r = 0; r < 4; ++r) {
        float4 v = *(const float4*)(src + (size_t)(kc + r) * H_ + ncol0 + m * 4);
        c[r][0] = v.x; c[r][1] = v.y; c[r][2] = v.z; c[r][3] = v.w;
    }
#pragma unroll
    for (int i = 0; i < 4; ++i) {
        u64t vh = 0, vl = 0;
#pragma unroll
        for (int r = 0; r < 4; ++r) {
            u16t h = f2bf(c[r][i]);
            u16t l2 = f2bf(c[r][i] - bf2f(h));
            vh |= (u64t)h << (16 * r);
            vl |= (u64t)l2 << (16 * r);
        }
        *(u64t*)(hi + (size_t)(4 * m + i) * 68 + kc) = vh;
        *(u64t*)(lo + (size_t)(4 * m + i) * 68 + kc) = vl;
    }
}

// bf16 src [64 k][128 h] (+ optional per-k mask) -> transposed [128 h][68] bf16 tile.
// 256 threads: m = t&31 -> h-group of 4, kq = t>>5 -> k-quad, 2 passes.
__device__ __forceinline__ void stage64_bf(const u16t* __restrict__ src,
                                           const int* __restrict__ maskrow,
                                           short* __restrict__ dst, int t) {
    const int m = t & 31, kq = t >> 5;
#pragma unroll
    for (int p = 0; p < 2; ++p) {
        const int kc = p * 32 + kq * 4;
        u64t q[4];
#pragma unroll
        for (int r = 0; r < 4; ++r) {
            u64t v = *(const u64t*)(src + (size_t)(kc + r) * H_ + m * 4);
            if (maskrow && !maskrow[kc + r]) v = 0;
            q[r] = v;
        }
#pragma unroll
        for (int i = 0; i < 4; ++i) {
            u64t val = ((q[0] >> (16 * i)) & 0xffffull)
                     | (((q[1] >> (16 * i)) & 0xffffull) << 16)
                     | (((q[2] >> (16 * i)) & 0xffffull) << 32)
                     | (((q[3] >> (16 * i)) & 0xffffull) << 48);
            *(u64t*)(dst + (size_t)(4 * m + i) * 68 + kc) = val;
        }
    }
}

// ---- unified MFMA GEMM: Y[row,:] = post( X[row,:] @ W[wsel] + bias ) ----
// X bf16 [*, 128]; W fp32 [*, 128k, 128n] split hi/lo in-kernel; 64row x 64col tiles.
// grid: (rowTiles, 2 n-halves, nW). mask: per-row multiplier (ctx); bias: per-col.
template<bool TANH, bool BF16OUT>
__global__ __launch_bounds__(256) void hgemm_hl_k(const u16t* __restrict__ Xall,
                                                  const float* __restrict__ Wall,
                                                  const float* __restrict__ biasAll,
                                                  const int* __restrict__ mask,
                                                  void* __restrict__ Yout,
                                                  int rowsPerW) {
    __shared__ __align__(16) short Hi0[64 * 68], Hi1[64 * 68];
    __shared__ __align__(16) short Lo0[64 * 68], Lo1[64 * 68];
    __shared__ __align__(16) short Xs[64 * 136];
    const int t = threadIdx.x;
    const int wsel = blockIdx.z, nh = blockIdx.y;
    const long row0 = (long)wsel * rowsPerW + (long)blockIdx.x * 64;
    const float* W = Wall + (size_t)wsel * HH_;

    stage64_hl(W, nh * 64, Hi0, Lo0, t);
    stage64_hl(W + 64 * H_, nh * 64, Hi1, Lo1, t);
    {
        const uint4* src = (const uint4*)(Xall + (size_t)row0 * H_);
#pragma unroll
        for (int j = 0; j < 4; ++j) {
            int lin = j * 256 + t;
            *(uint4*)(Xs + (lin >> 4) * 136 + (lin & 15) * 8) = src[lin];
        }
    }
    __syncthreads();

    const int l = t & 63, w = t >> 6;
    const int lm = l & 15, lk = (l >> 4) * 8, lr = (l >> 4) * 4;
    const int cl = w * 16 + lm;  // local col (this wave owns 16 cols)
    f32x4 acc[4] = {};
#pragma unroll
    for (int ks = 0; ks < 128; ks += 32) {
        const short* Hi = (ks & 64) ? Hi1 : Hi0;
        const short* Lo = (ks & 64) ? Lo1 : Lo0;
        const int kk = ks & 32;
        bf16x8 bh = ldfragS(Hi, cl, kk + lk, 68);
        bf16x8 bl = ldfragS(Lo, cl, kk + lk, 68);
#pragma unroll
        for (int it = 0; it < 4; ++it) {
            bf16x8 af = ldfragS(Xs, it * 16 + lm, ks + lk, 136);
            acc[it] = __builtin_amdgcn_mfma_f32_16x16x32_bf16(af, bh, acc[it], 0, 0, 0);
            acc[it] = __builtin_amdgcn_mfma_f32_16x16x32_bf16(af, bl, acc[it], 0, 0, 0);
        }
    }

    const int colg = nh * 64 + w * 16 + lm;
    const float bv = biasAll ? biasAll[colg] : 0.f;
#pragma unroll
    for (int it = 0; it < 4; ++it) {
#pragma unroll
        for (int r = 0; r < 4; ++r) {
            long row = row0 + it * 16 + lr + r;
            float v = acc[it][r] + bv;
            if (TANH) v = ftanh(v);
            if (mask) v *= (float)mask[row];
            if (BF16OUT) ((u16t*)Yout)[(size_t)row * H_ + colg] = f2bf(v);
            else ((float*)Yout)[(size_t)row * H_ + colg] = v;
        }
    }
}

// part[slice*B+b] = sum over slice's k of (mask*Xl[k,:])^T outer Yr[k,:], bf16 MFMA.
template<bool SAME>
__global__ __launch_bounds__(256) void syrk_mfma_k(const u16t* __restrict__ Xl,
                                                   const u16t* __restrict__ Yr,
                                                   const int* __restrict__ mask,
                                                   float* __restrict__ part,
                                                   int Kb, int rowsPerSlice) {
    extern __shared__ short smem[];
    short* Xt = smem;
    short* Yt = SAME ? smem : (smem + 128 * 68);
    const int t = threadIdx.x;
    const int b = blockIdx.y, slice = blockIdx.x;
    const int l = t & 63, w = t >> 6;
    const int qi = (w >> 1) * 64, qj = (w & 1) * 64;
    const int lm = l & 15, lk = (l >> 4) * 8, lr = (l >> 4) * 4;

    f32x4 acc[4][4] = {};
    const int chunks = rowsPerSlice >> 6;
    const size_t boff = (size_t)b * Kb;

    for (int c = 0; c < chunks; ++c) {
        const int kbase = slice * rowsPerSlice + c * 64;
        stage64_bf(Xl + (boff + kbase) * H_, mask + boff + kbase, Xt, t);
        if (!SAME) stage64_bf(Yr + (boff + kbase) * H_, nullptr, Yt, t);
        __syncthreads();
#pragma unroll
        for (int ks = 0; ks < 64; ks += 32) {
            bf16x8 af[4], bfr[4];
#pragma unroll
            for (int it = 0; it < 4; ++it) af[it] = ldfragS(Xt, qi + it * 16 + lm, ks + lk, 68);
#pragma unroll
            for (int jt = 0; jt < 4; ++jt) bfr[jt] = ldfragS(Yt, qj + jt * 16 + lm, ks + lk, 68);
#pragma unroll
            for (int it = 0; it < 4; ++it)
#pragma unroll
                for (int jt = 0; jt < 4; ++jt)
                    acc[it][jt] = __builtin_amdgcn_mfma_f32_16x16x32_bf16(
                        af[it], bfr[jt], acc[it][jt], 0, 0, 0);
        }
        __syncthreads();
    }

    float* pb = part + ((size_t)slice * B_ + b) * HH_;
#pragma unroll
    for (int it = 0; it < 4; ++it)
#pragma unroll
        for (int jt = 0; jt < 4; ++jt)
#pragma unroll
            for (int r = 0; r < 4; ++r)
                pb[(size_t)(qi + it * 16 + lr + r) * H_ + qj + jt * 16 + lm] = acc[it][jt][r];
}

__global__ __launch_bounds__(256) void reduce_k(const float4* __restrict__ part,
                                                float4* __restrict__ out, int slices) {
    const int idx = blockIdx.x * 256 + threadIdx.x;
    float4 a = part[idx];
    for (int s = 1; s < slices; ++s) {
        float4 v = part[(size_t)s * (B_ * HH_ / 4) + idx];
        a.x += v.x; a.y += v.y; a.z += v.z; a.w += v.w;
    }
    out[idx] = a;
}

__global__ void tobf16_k(const float4* __restrict__ in, uint4* __restrict__ out) {
    int idx = blockIdx.x * 256 + threadIdx.x;
    float4 a = in[2 * idx], b = in[2 * idx + 1];
    uint4 o;
    o.x = (unsigned)f2bf(a.x) | ((unsigned)f2bf(a.y) << 16);
    o.y = (unsigned)f2bf(a.z) | ((unsigned)f2bf(a.w) << 16);
    o.z = (unsigned)f2bf(b.x) | ((unsigned)f2bf(b.y) << 16);
    o.w = (unsigned)f2bf(b.z) | ((unsigned)f2bf(b.w) << 16);
    out[idx] = o;
}

// ---- vc[b] = M[b] @ Wac ; vp[b] = N[b] @ Wap ----
__global__ void mv_k(const float* __restrict__ M, const float* __restrict__ N,
                     const float* __restrict__ Wac, const float* __restrict__ Wap,
                     float* __restrict__ vc, float* __restrict__ vp) {
    int b = blockIdx.x, t = threadIdx.x;
    const float* mat = (t < 128) ? (M + (size_t)b * HH_ + (size_t)t * H_)
                                 : (N + (size_t)b * HH_ + (size_t)(t - 128) * H_);
    const float* w = (t < 128) ? Wac : Wap;
    float acc = 0.f;
#pragma unroll 8
    for (int h = 0; h < H_; ++h) acc = fmaf(mat[h], w[h], acc);
    if (t < 128) vc[b * H_ + t] = acc;
    else         vp[b * H_ + (t - 128)] = acc;
}

// ---- logits[b,r] = mask[b,r] * (feat_bf16[b,r,:] . v[b]) + bias ----
__global__ void logits_k(const u16t* __restrict__ feat, const int* __restrict__ mask,
                         const float* __restrict__ v, const float* __restrict__ biasPtr,
                         float* __restrict__ out, int n) {
    int idx = blockIdx.x * blockDim.x + threadIdx.x;
    int b = idx / n;
    const uint2* r2 = (const uint2*)(feat + (size_t)idx * H_);
    const float4* v4 = (const float4*)(v + (size_t)b * H_);
    float acc = 0.f;
#pragma unroll
    for (int h4 = 0; h4 < 32; ++h4) {
        uint2 u = r2[h4];
        float4 c = v4[h4];
        acc = fmaf(bflo(u.x), c.x, acc); acc = fmaf(bfhi(u.x), c.y, acc);
        acc = fmaf(bflo(u.y), c.z, acc); acc = fmaf(bfhi(u.y), c.w, acc);
    }
    out[idx] = (float)mask[idx] * acc + biasPtr[0];
}

// ---- masked softmax, faithful: max over ALL, exp*mask, denom + 1e-6 ----
__global__ __launch_bounds__(256) void softmax_k(const float* __restrict__ logits,
                                                 const int* __restrict__ mask,
                                                 float* __restrict__ w, int n) {
    int b = blockIdx.x, t = threadIdx.x;
    const float* l = logits + (size_t)b * n;
    const int* mk = mask + (size_t)b * n;
    float* ww = w + (size_t)b * n;
    __shared__ float Es[4096];
    __shared__ float red[4];

    float mx = -1e30f;
    for (int q = t; q < n; q += 256) mx = fmaxf(mx, l[q]);
#pragma unroll
    for (int o = 32; o > 0; o >>= 1) mx = fmaxf(mx, __shfl_down(mx, o, 64));
    if ((t & 63) == 0) red[t >> 6] = mx;
    __syncthreads();
    float m = fmaxf(fmaxf(red[0], red[1]), fmaxf(red[2], red[3]));
    __syncthreads();

    float s = 0.f;
    for (int q = t; q < n; q += 256) {
        float e = __expf(l[q] - m) * (float)mk[q];
        Es[q] = e;
        s += e;
    }
#pragma unroll
    for (int o = 32; o > 0; o >>= 1) s += __shfl_down(s, o, 64);
    if ((t & 63) == 0) red[t >> 6] = s;
    __syncthreads();
    float denom = red[0] + red[1] + red[2] + red[3] + 1e-6f;
    for (int q = t; q < n; q += 256) ww[q] = Es[q] / denom;
}

// ---- pooled[b,h] += sum_{q in chunk} proj_bf16[b,q,h] * w[b,q] ----
__global__ void pool_k(const u16t* __restrict__ proj, const float* __restrict__ w,
                       float* __restrict__ out, int n, int chunk) {
    int b = blockIdx.x, h = threadIdx.x;
    int q0 = blockIdx.y * chunk;
    const u16t* pb = proj + ((size_t)b * n + q0) * H_;
    const float* wb = w + (size_t)b * n + q0;
    float acc = 0.f;
#pragma unroll 4
    for (int q = 0; q < chunk; ++q) acc = fmaf(bf2f(pb[(size_t)q * H_ + h]), wb[q], acc);
    atomicAdd(&out[b * H_ + h], acc);
}

// ---- final[b,h] = concat(pooled[0..2])[b,:] @ Wcomb + bcomb ----
__global__ void final_k(const float* __restrict__ pooled, const float* __restrict__ Wcomb,
                        const float* __restrict__ bcomb, float* __restrict__ out) {
    int b = blockIdx.x, h = threadIdx.x;
    float acc = bcomb[h];
#pragma unroll 4
    for (int j = 0; j < 3 * H_; ++j) {
        int lay = j >> 7, hh = j & 127;
        acc = fmaf(pooled[((size_t)lay * B_ + b) * H_ + hh], Wcomb[j * H_ + h], acc);
    }
    out[b * H_ + h] = acc;
}

extern "C" void kernel_launch(void* const* d_in, const int* in_sizes, int n_in,
                              void* d_out, int out_size, void* d_ws, size_t ws_size,
                              hipStream_t stream) {
    const float* comp_feat = (const float*)d_in[0];
    const int*   comp_mask = (const int*)d_in[1];
    const float* prot_feat = (const float*)d_in[2];
    const int*   prot_mask = (const int*)d_in[3];
    const float* Wc      = (const float*)d_in[4];
    const float* bc      = (const float*)d_in[5];
    const float* Wp      = (const float*)d_in[6];
    const float* bp      = (const float*)d_in[7];
    const float* Wbl     = (const float*)d_in[8];
    const float* Wac     = (const float*)d_in[9];
    const float* bac     = (const float*)d_in[10];
    const float* Wap     = (const float*)d_in[11];
    const float* bap     = (const float*)d_in[12];
    const float* Wcomb_c = (const float*)d_in[13];
    const float* bcomb_c = (const float*)d_in[14];
    const float* Wcomb_p = (const float*)d_in[15];
    const float* bcomb_p = (const float*)d_in[16];

    // ---- workspace layout: bf16 region first, then fp32 region ----
    u16t* prot_feat_bf = (u16t*)d_ws;                                  // 16*4096*128
    u16t* comp_feat_bf = prot_feat_bf + (size_t)B_ * LP_ * H_;         // 16*512*128
    u16t* prot_proj_bf = comp_feat_bf + (size_t)B_ * LC_ * H_;         // 16*4096*128
    u16t* comp_proj_bf = prot_proj_bf + (size_t)B_ * LP_ * H_;         // 16*512*128
    u16t* comp_bil_bf  = comp_proj_bf + (size_t)B_ * LC_ * H_;         // 16*512*128
    float* f = (float*)(comp_bil_bf + (size_t)B_ * LC_ * H_);
    float* Mbuf = f; f += (size_t)B_ * HH_;
    float* Nbuf = f; f += (size_t)B_ * HH_;
    float* vc = f;   f += B_ * H_;
    float* vp = f;   f += B_ * H_;
    float* logc = f; f += B_ * LC_;
    float* logp = f; f += B_ * LP_;
    float* cw = f;   f += B_ * LC_;
    float* pw = f;   f += B_ * LP_;
    float* cp = f;   f += 3 * B_ * H_;
    float* pp = f;   f += 3 * B_ * H_;

    float* out_cf = (float*)d_out;
    float* out_pf = out_cf + B_ * H_;
    float* out_cc = out_pf + B_ * H_;
    float* out_pc = out_cc + (size_t)B_ * LC_ * H_;

    // out_pc (33.5MB) doubles as the syrk partial buffer until layer 2's epilogue.
    float* part = out_pc;
    const int SLICES_P = 32;  // 128 k-rows/slice
    const int SLICES_C = 8;   // 64 k-rows/slice

    tobf16_k<<<dim3(B_ * LP_ * H_ / 8 / 256), 256, 0, stream>>>(
        (const float4*)prot_feat, (uint4*)prot_feat_bf);
    tobf16_k<<<dim3(B_ * LC_ * H_ / 8 / 256), 256, 0, stream>>>(
        (const float4*)comp_feat, (uint4*)comp_feat_bf);
    hipMemsetAsync(cp, 0, 2 * 3 * (size_t)B_ * H_ * sizeof(float), stream);

    for (int i = 0; i < 3; ++i) {
        // projections (tanh) + bilinear, all bf16-out MFMA
        hgemm_hl_k<true, true><<<dim3(B_ * LP_ / 64, 2, 1), 256, 0, stream>>>(
            prot_feat_bf, Wp + (size_t)i * HH_, bp + i * H_, nullptr, prot_proj_bf, B_ * LP_);
        hgemm_hl_k<true, true><<<dim3(B_ * LC_ / 64, 2, 1), 256, 0, stream>>>(
            comp_feat_bf, Wc + (size_t)i * HH_, bc + i * H_, nullptr, comp_proj_bf, B_ * LC_);
        hgemm_hl_k<false, true><<<dim3(B_ * LC_ / 64, 2, 1), 256, 0, stream>>>(
            comp_proj_bf, Wbl + (size_t)i * HH_, nullptr, nullptr, comp_bil_bf, B_ * LC_);

        // M = P^T diag(pm) P ; N = Bil^T diag(cm) Cproj
        syrk_mfma_k<true><<<dim3(SLICES_P, B_), 256, 128 * 68 * sizeof(short), stream>>>(
            prot_proj_bf, prot_proj_bf, prot_mask, part, LP_, LP_ / SLICES_P);
        reduce_k<<<dim3(B_ * HH_ / 4 / 256), 256, 0, stream>>>(
            (const float4*)part, (float4*)Mbuf, SLICES_P);
        syrk_mfma_k<false><<<dim3(SLICES_C, B_), 256, 2 * 128 * 68 * sizeof(short), stream>>>(
            comp_bil_bf, comp_proj_bf, comp_mask, part, LC_, LC_ / SLICES_C);
        reduce_k<<<dim3(B_ * HH_ / 4 / 256), 256, 0, stream>>>(
            (const float4*)part, (float4*)Nbuf, SLICES_C);

        mv_k<<<dim3(B_), 256, 0, stream>>>(Mbuf, Nbuf, Wac + i * H_, Wap + i * H_, vc, vp);

        logits_k<<<dim3(B_ * LC_ / 256), 256, 0, stream>>>(comp_bil_bf, comp_mask, vc, bac + i, logc, LC_);
        logits_k<<<dim3(B_ * LP_ / 256), 256, 0, stream>>>(prot_proj_bf, prot_mask, vp, bap + i, logp, LP_);

        softmax_k<<<dim3(B_), 256, 0, stream>>>(logc, comp_mask, cw, LC_);
        softmax_k<<<dim3(B_), 256, 0, stream>>>(logp, prot_mask, pw, LP_);

        pool_k<<<dim3(B_, 2), 128, 0, stream>>>(comp_proj_bf, cw, cp + (size_t)i * B_ * H_, LC_, 256);
        pool_k<<<dim3(B_, 8), 128, 0, stream>>>(prot_proj_bf, pw, pp + (size_t)i * B_ * H_, LP_, 512);

        if (i == 2) {
            hgemm_hl_k<false, false><<<dim3(LC_ / 64, 2, B_), 256, 0, stream>>>(
                comp_bil_bf, Mbuf, nullptr, comp_mask, out_cc, LC_);
            hgemm_hl_k<false, false><<<dim3(LP_ / 64, 2, B_), 256, 0, stream>>>(
                prot_proj_bf, Nbuf, nullptr, prot_mask, out_pc, LP_);
        }
    }

    final_k<<<dim3(B_), 128, 0, stream>>>(cp, Wcomb_c, bcomb_c, out_cf);
    final_k<<<dim3(B_), 128, 0, stream>>>(pp, Wcomb_p, bcomb_p, out_pf);
}

// Round 6
// 273.432 us; speedup vs baseline: 2.5658x; 1.9092x over previous
//
#include <hip/hip_runtime.h>
#include <math.h>

#define B_ 16
#define LC_ 512
#define LP_ 4096
#define H_ 128
#define HH_ (H_*H_)

typedef unsigned long long u64t;
typedef unsigned short u16t;
typedef __attribute__((ext_vector_type(8))) short bf16x8;
typedef __attribute__((ext_vector_type(4))) float f32x4;

__device__ __forceinline__ u16t f2bf(float f) {
    union { float f; unsigned u; } v; v.f = f;
    unsigned r = (v.u + 0x7FFFu + ((v.u >> 16) & 1u)) >> 16;
    return (u16t)r;
}
__device__ __forceinline__ float bf2f(u16t s) {
    union { unsigned u; float f; } v; v.u = ((unsigned)s) << 16; return v.f;
}
__device__ __forceinline__ float bflo(unsigned u) {
    union { unsigned u; float f; } v; v.u = u << 16; return v.f;
}
__device__ __forceinline__ float bfhi(unsigned u) {
    union { unsigned u; float f; } v; v.u = u & 0xffff0000u; return v.f;
}
__device__ __forceinline__ float ftanh(float x) {
    x = fminf(15.f, fmaxf(-15.f, x));
    float t = __expf(2.f * x);
    return (t - 1.f) / (t + 1.f);
}
__device__ __forceinline__ bf16x8 ldfragS(const short* base, int r, int k, int stride) {
    const u64t* p = (const u64t*)(base + (size_t)r * stride + k);
    union { bf16x8 v; u64t q[2]; } u;
    u.q[0] = p[0]; u.q[1] = p[1];
    return u.v;
}

// fp32 W rows [64 k][128 n] -> transposed bf16 hi/lo tiles [64 n][68], cols ncol0..+63.
__device__ __forceinline__ void stage64_hl(const float* __restrict__ src, int ncol0,
                                           short* __restrict__ hi, short* __restrict__ lo,
                                           int t) {
    const int m = t & 15, kq = t >> 4;
    const int kc = kq * 4;
    float c[4][4];
#pragma unroll
    for (int r = 0; r < 4; ++r) {
        float4 v = *(const float4*)(src + (size_t)(kc + r) * H_ + ncol0 + m * 4);
        c[r][0] = v.x; c[r][1] = v.y; c[r][2] = v.z; c[r][3] = v.w;
    }
#pragma unroll
    for (int i = 0; i < 4; ++i) {
        u64t vh = 0, vl = 0;
#pragma unroll
        for (int r = 0; r < 4; ++r) {
            u16t h = f2bf(c[r][i]);
            u16t l2 = f2bf(c[r][i] - bf2f(h));
            vh |= (u64t)h << (16 * r);
            vl |= (u64t)l2 << (16 * r);
        }
        *(u64t*)(hi + (size_t)(4 * m + i) * 68 + kc) = vh;
        *(u64t*)(lo + (size_t)(4 * m + i) * 68 + kc) = vl;
    }
}

// bf16 src [64 k][128 h] (+ optional per-k mask) -> transposed [128 h][68] bf16 tile.
__device__ __forceinline__ void stage64_bf(const u16t* __restrict__ src,
                                           const int* __restrict__ maskrow,
                                           short* __restrict__ dst, int t) {
    const int m = t & 31, kq = t >> 5;
#pragma unroll
    for (int p = 0; p < 2; ++p) {
        const int kc = p * 32 + kq * 4;
        u64t q[4];
#pragma unroll
        for (int r = 0; r < 4; ++r) {
            u64t v = *(const u64t*)(src + (size_t)(kc + r) * H_ + m * 4);
            if (maskrow && !maskrow[kc + r]) v = 0;
            q[r] = v;
        }
#pragma unroll
        for (int i = 0; i < 4; ++i) {
            u64t val = ((q[0] >> (16 * i)) & 0xffffull)
                     | (((q[1] >> (16 * i)) & 0xffffull) << 16)
                     | (((q[2] >> (16 * i)) & 0xffffull) << 32)
                     | (((q[3] >> (16 * i)) & 0xffffull) << 48);
            *(u64t*)(dst + (size_t)(4 * m + i) * 68 + kc) = val;
        }
    }
}

// ---- unified MFMA GEMM: Y[wsel-unit row,:] = post( X @ W[wsel] + bias[wsel?] ) ----
// grid: (rows/64, 2 n-halves, nWsel). XPERW: X also strided by wsel (else shared).
template<bool TANH, bool BF16OUT, bool XPERW, bool BIASPERW>
__global__ __launch_bounds__(256) void hgemm_hl_k(const u16t* __restrict__ Xall,
                                                  const float* __restrict__ Wall,
                                                  const float* __restrict__ biasAll,
                                                  const int* __restrict__ mask,
                                                  void* __restrict__ Yout,
                                                  int rows) {
    __shared__ __align__(16) short Hi0[64 * 68], Hi1[64 * 68];
    __shared__ __align__(16) short Lo0[64 * 68], Lo1[64 * 68];
    __shared__ __align__(16) short Xs[64 * 136];
    const int t = threadIdx.x;
    const int wsel = blockIdx.z, nh = blockIdx.y;
    const long yrow0 = (long)wsel * rows + (long)blockIdx.x * 64;
    const u16t* X = XPERW ? (Xall + (size_t)yrow0 * H_)
                          : (Xall + (size_t)blockIdx.x * 64 * H_);
    const float* W = Wall + (size_t)wsel * HH_;

    stage64_hl(W, nh * 64, Hi0, Lo0, t);
    stage64_hl(W + 64 * H_, nh * 64, Hi1, Lo1, t);
    {
        const uint4* src = (const uint4*)X;
#pragma unroll
        for (int j = 0; j < 4; ++j) {
            int lin = j * 256 + t;
            *(uint4*)(Xs + (lin >> 4) * 136 + (lin & 15) * 8) = src[lin];
        }
    }
    __syncthreads();

    const int l = t & 63, w = t >> 6;
    const int lm = l & 15, lk = (l >> 4) * 8, lr = (l >> 4) * 4;
    const int cl = w * 16 + lm;
    f32x4 acc[4] = {};
#pragma unroll
    for (int ks = 0; ks < 128; ks += 32) {
        const short* Hi = (ks & 64) ? Hi1 : Hi0;
        const short* Lo = (ks & 64) ? Lo1 : Lo0;
        const int kk = ks & 32;
        bf16x8 bh = ldfragS(Hi, cl, kk + lk, 68);
        bf16x8 bl = ldfragS(Lo, cl, kk + lk, 68);
#pragma unroll
        for (int it = 0; it < 4; ++it) {
            bf16x8 af = ldfragS(Xs, it * 16 + lm, ks + lk, 136);
            acc[it] = __builtin_amdgcn_mfma_f32_16x16x32_bf16(af, bh, acc[it], 0, 0, 0);
            acc[it] = __builtin_amdgcn_mfma_f32_16x16x32_bf16(af, bl, acc[it], 0, 0, 0);
        }
    }

    const int colg = nh * 64 + w * 16 + lm;
    const float bv = biasAll ? biasAll[(BIASPERW ? wsel * H_ : 0) + colg] : 0.f;
#pragma unroll
    for (int it = 0; it < 4; ++it) {
#pragma unroll
        for (int r = 0; r < 4; ++r) {
            long row = yrow0 + it * 16 + lr + r;
            float v = acc[it][r] + bv;
            if (TANH) v = ftanh(v);
            if (mask) v *= (float)mask[row];
            if (BF16OUT) ((u16t*)Yout)[(size_t)row * H_ + colg] = f2bf(v);
            else ((float*)Yout)[(size_t)row * H_ + colg] = v;
        }
    }
}

// part[lay][slice][b] = sum over slice's k of (mask*Xl[lay,b,k,:])^T outer Yr[lay,b,k,:]
template<bool SAME>
__global__ __launch_bounds__(256) void syrk_mfma_k(const u16t* __restrict__ Xl,
                                                   const u16t* __restrict__ Yr,
                                                   const int* __restrict__ mask,
                                                   float* __restrict__ part,
                                                   int Kb, int rowsPerSlice, int slices) {
    extern __shared__ short smem[];
    short* Xt = smem;
    short* Yt = SAME ? smem : (smem + 128 * 68);
    const int t = threadIdx.x;
    const int b = blockIdx.y, slice = blockIdx.x, lay = blockIdx.z;
    const int l = t & 63, w = t >> 6;
    const int qi = (w >> 1) * 64, qj = (w & 1) * 64;
    const int lm = l & 15, lk = (l >> 4) * 8, lr = (l >> 4) * 4;

    f32x4 acc[4][4] = {};
    const int chunks = rowsPerSlice >> 6;
    const size_t doff = ((size_t)lay * B_ + b) * Kb;
    const size_t moff = (size_t)b * Kb;

    for (int c = 0; c < chunks; ++c) {
        const int kbase = slice * rowsPerSlice + c * 64;
        stage64_bf(Xl + (doff + kbase) * H_, mask + moff + kbase, Xt, t);
        if (!SAME) stage64_bf(Yr + (doff + kbase) * H_, nullptr, Yt, t);
        __syncthreads();
#pragma unroll
        for (int ks = 0; ks < 64; ks += 32) {
            bf16x8 af[4], bfr[4];
#pragma unroll
            for (int it = 0; it < 4; ++it) af[it] = ldfragS(Xt, qi + it * 16 + lm, ks + lk, 68);
#pragma unroll
            for (int jt = 0; jt < 4; ++jt) bfr[jt] = ldfragS(Yt, qj + jt * 16 + lm, ks + lk, 68);
#pragma unroll
            for (int it = 0; it < 4; ++it)
#pragma unroll
                for (int jt = 0; jt < 4; ++jt)
                    acc[it][jt] = __builtin_amdgcn_mfma_f32_16x16x32_bf16(
                        af[it], bfr[jt], acc[it][jt], 0, 0, 0);
        }
        __syncthreads();
    }

    float* pb = part + (((size_t)lay * slices + slice) * B_ + b) * HH_;
#pragma unroll
    for (int it = 0; it < 4; ++it)
#pragma unroll
        for (int jt = 0; jt < 4; ++jt)
#pragma unroll
            for (int r = 0; r < 4; ++r)
                pb[(size_t)(qi + it * 16 + lr + r) * H_ + qj + jt * 16 + lm] = acc[it][jt][r];
}

__global__ __launch_bounds__(256) void reduce_k(const float4* __restrict__ part,
                                                float4* __restrict__ out, int slices) {
    const int lay = blockIdx.y;
    const size_t idx = (size_t)blockIdx.x * 256 + threadIdx.x;
    const size_t quarter = (size_t)B_ * HH_ / 4;
    const float4* p = part + (size_t)lay * slices * quarter;
    float4 a = p[idx];
    for (int s = 1; s < slices; ++s) {
        float4 v = p[(size_t)s * quarter + idx];
        a.x += v.x; a.y += v.y; a.z += v.z; a.w += v.w;
    }
    (out + (size_t)lay * quarter)[idx] = a;
}

__global__ void tobf16_k(const float4* __restrict__ in, uint4* __restrict__ out) {
    int idx = blockIdx.x * 256 + threadIdx.x;
    float4 a = in[2 * idx], b = in[2 * idx + 1];
    uint4 o;
    o.x = (unsigned)f2bf(a.x) | ((unsigned)f2bf(a.y) << 16);
    o.y = (unsigned)f2bf(a.z) | ((unsigned)f2bf(a.w) << 16);
    o.z = (unsigned)f2bf(b.x) | ((unsigned)f2bf(b.y) << 16);
    o.w = (unsigned)f2bf(b.z) | ((unsigned)f2bf(b.w) << 16);
    out[idx] = o;
}

// ---- fused per-(b,layer): v = M@Wv; logits = mask*(feat.v)+bias; masked softmax ----
template<int N>
__global__ __launch_bounds__(256) void attn_k(const float* __restrict__ Mall,
                                              const float* __restrict__ WvAll,
                                              const float* __restrict__ bvAll,
                                              const u16t* __restrict__ featAll,
                                              const int* __restrict__ maskAll,
                                              float* __restrict__ wOut) {
    __shared__ float v[H_];
    __shared__ float Es[N];
    __shared__ float red[4];
    const int b = blockIdx.x, lay = blockIdx.y, t = threadIdx.x;

    if (t < 128) {
        const float4* mr = (const float4*)(Mall + ((size_t)lay * B_ + b) * HH_ + (size_t)t * H_);
        const float4* wr = (const float4*)(WvAll + lay * H_);
        float a = 0.f;
#pragma unroll
        for (int h4 = 0; h4 < 32; ++h4) {
            float4 x = mr[h4], c = wr[h4];
            a = fmaf(x.x, c.x, a); a = fmaf(x.y, c.y, a);
            a = fmaf(x.z, c.z, a); a = fmaf(x.w, c.w, a);
        }
        v[t] = a;
    }
    __syncthreads();

    const u16t* feat = featAll + ((size_t)lay * B_ + b) * (size_t)N * H_;
    const int* mk = maskAll + (size_t)b * N;
    const float bias = bvAll[lay];
    const float4* v4 = (const float4*)v;

    float mx = -1e30f;
    for (int r = t; r < N; r += 256) {
        const uint2* f2 = (const uint2*)(feat + (size_t)r * H_);
        float acc = 0.f;
#pragma unroll
        for (int h4 = 0; h4 < 32; ++h4) {
            uint2 u = f2[h4];
            float4 c = v4[h4];
            acc = fmaf(bflo(u.x), c.x, acc); acc = fmaf(bfhi(u.x), c.y, acc);
            acc = fmaf(bflo(u.y), c.z, acc); acc = fmaf(bfhi(u.y), c.w, acc);
        }
        float l = (float)mk[r] * acc + bias;
        Es[r] = l;
        mx = fmaxf(mx, l);
    }
#pragma unroll
    for (int o = 32; o > 0; o >>= 1) mx = fmaxf(mx, __shfl_down(mx, o, 64));
    if ((t & 63) == 0) red[t >> 6] = mx;
    __syncthreads();
    float m = fmaxf(fmaxf(red[0], red[1]), fmaxf(red[2], red[3]));
    __syncthreads();

    float s = 0.f;
    for (int r = t; r < N; r += 256) {
        float e = __expf(Es[r] - m) * (float)mk[r];
        Es[r] = e;
        s += e;
    }
#pragma unroll
    for (int o = 32; o > 0; o >>= 1) s += __shfl_down(s, o, 64);
    if ((t & 63) == 0) red[t >> 6] = s;
    __syncthreads();
    float denom = red[0] + red[1] + red[2] + red[3] + 1e-6f;
    float* ww = wOut + ((size_t)lay * B_ + b) * N;
    for (int r = t; r < N; r += 256) ww[r] = Es[r] / denom;
}

// ---- pooled[lay,b,h] += sum_{q in chunk} proj_bf16[lay,b,q,h] * w[lay,b,q] ----
__global__ void pool_k(const u16t* __restrict__ proj, const float* __restrict__ w,
                       float* __restrict__ out, int n, int chunk) {
    const int b = blockIdx.x, h = threadIdx.x, lay = blockIdx.z;
    const int q0 = blockIdx.y * chunk;
    const u16t* pb = proj + (((size_t)lay * B_ + b) * n + q0) * H_;
    const float* wb = w + ((size_t)lay * B_ + b) * n + q0;
    float acc = 0.f;
#pragma unroll 4
    for (int q = 0; q < chunk; ++q) acc = fmaf(bf2f(pb[(size_t)q * H_ + h]), wb[q], acc);
    atomicAdd(&out[((size_t)lay * B_ + b) * H_ + h], acc);
}

// ---- final[b,h] += sum_{j in chunk} pooled[j>>7, b, j&127] * Wcomb[j,h] (+bias) ----
__global__ void final2_k(const float* __restrict__ pooled, const float* __restrict__ Wcomb,
                         const float* __restrict__ bcomb, float* __restrict__ out) {
    const int b = blockIdx.x, h = threadIdx.x, j0 = blockIdx.y * 64;
    float acc = (blockIdx.y == 0) ? bcomb[h] : 0.f;
#pragma unroll 4
    for (int j = 0; j < 64; ++j) {
        int jj = j0 + j;
        int lay = jj >> 7, hh = jj & 127;
        acc = fmaf(pooled[((size_t)lay * B_ + b) * H_ + hh], Wcomb[(size_t)jj * H_ + h], acc);
    }
    atomicAdd(&out[b * H_ + h], acc);
}

extern "C" void kernel_launch(void* const* d_in, const int* in_sizes, int n_in,
                              void* d_out, int out_size, void* d_ws, size_t ws_size,
                              hipStream_t stream) {
    const float* comp_feat = (const float*)d_in[0];
    const int*   comp_mask = (const int*)d_in[1];
    const float* prot_feat = (const float*)d_in[2];
    const int*   prot_mask = (const int*)d_in[3];
    const float* Wc      = (const float*)d_in[4];
    const float* bc      = (const float*)d_in[5];
    const float* Wp      = (const float*)d_in[6];
    const float* bp      = (const float*)d_in[7];
    const float* Wbl     = (const float*)d_in[8];
    const float* Wac     = (const float*)d_in[9];
    const float* bac     = (const float*)d_in[10];
    const float* Wap     = (const float*)d_in[11];
    const float* bap     = (const float*)d_in[12];
    const float* Wcomb_c = (const float*)d_in[13];
    const float* bcomb_c = (const float*)d_in[14];
    const float* Wcomb_p = (const float*)d_in[15];
    const float* bcomb_p = (const float*)d_in[16];

    // ---- workspace: bf16 region, then fp32 region (~115 MB total) ----
    u16t* prot_feat_bf = (u16t*)d_ws;                                    // B*LP*H
    u16t* comp_feat_bf = prot_feat_bf + (size_t)B_ * LP_ * H_;           // B*LC*H
    u16t* prot_proj_bf = comp_feat_bf + (size_t)B_ * LC_ * H_;           // 3*B*LP*H
    u16t* comp_proj_bf = prot_proj_bf + (size_t)3 * B_ * LP_ * H_;       // 3*B*LC*H
    u16t* comp_bil_bf  = comp_proj_bf + (size_t)3 * B_ * LC_ * H_;       // 3*B*LC*H
    float* f = (float*)(comp_bil_bf + (size_t)3 * B_ * LC_ * H_);
    float* Mbuf = f; f += (size_t)3 * B_ * HH_;
    float* Nbuf = f; f += (size_t)3 * B_ * HH_;
    float* cw = f;   f += (size_t)3 * B_ * LC_;
    float* pw = f;   f += (size_t)3 * B_ * LP_;
    float* cp = f;   f += 3 * B_ * H_;
    float* pp = f;   f += 3 * B_ * H_;
    float* part = f; // 3 * 8 * B * HH floats = 25.2 MB

    float* out_cf = (float*)d_out;
    float* out_pf = out_cf + B_ * H_;
    float* out_cc = out_pf + B_ * H_;
    float* out_pc = out_cc + (size_t)B_ * LC_ * H_;

    const int SL = 8;  // syrk slices (both sides); layer batching supplies blocks

    tobf16_k<<<dim3(B_ * LP_ * H_ / 8 / 256), 256, 0, stream>>>(
        (const float4*)prot_feat, (uint4*)prot_feat_bf);
    tobf16_k<<<dim3(B_ * LC_ * H_ / 8 / 256), 256, 0, stream>>>(
        (const float4*)comp_feat, (uint4*)comp_feat_bf);
    hipMemsetAsync(cp, 0, (size_t)2 * 3 * B_ * H_ * sizeof(float), stream);
    hipMemsetAsync(d_out, 0, (size_t)2 * B_ * H_ * sizeof(float), stream);

    // projections (all 3 layers batched in grid z)
    hgemm_hl_k<true, true, false, true><<<dim3(B_ * LP_ / 64, 2, 3), 256, 0, stream>>>(
        prot_feat_bf, Wp, bp, nullptr, prot_proj_bf, B_ * LP_);
    hgemm_hl_k<true, true, false, true><<<dim3(B_ * LC_ / 64, 2, 3), 256, 0, stream>>>(
        comp_feat_bf, Wc, bc, nullptr, comp_proj_bf, B_ * LC_);
    hgemm_hl_k<false, true, true, false><<<dim3(B_ * LC_ / 64, 2, 3), 256, 0, stream>>>(
        comp_proj_bf, Wbl, nullptr, nullptr, comp_bil_bf, B_ * LC_);

    // M[lay] = P^T diag(pm) P
    syrk_mfma_k<true><<<dim3(SL, B_, 3), 256, 128 * 68 * sizeof(short), stream>>>(
        prot_proj_bf, prot_proj_bf, prot_mask, part, LP_, LP_ / SL, SL);
    reduce_k<<<dim3(B_ * HH_ / 4 / 256, 3), 256, 0, stream>>>(
        (const float4*)part, (float4*)Mbuf, SL);
    // N[lay] = Bil^T diag(cm) Cproj
    syrk_mfma_k<false><<<dim3(SL, B_, 3), 256, 2 * 128 * 68 * sizeof(short), stream>>>(
        comp_bil_bf, comp_proj_bf, comp_mask, part, LC_, LC_ / SL, SL);
    reduce_k<<<dim3(B_ * HH_ / 4 / 256, 3), 256, 0, stream>>>(
        (const float4*)part, (float4*)Nbuf, SL);

    // fused v + logits + masked softmax
    attn_k<LC_><<<dim3(B_, 3), 256, 0, stream>>>(Mbuf, Wac, bac, comp_bil_bf, comp_mask, cw);
    attn_k<LP_><<<dim3(B_, 3), 256, 0, stream>>>(Nbuf, Wap, bap, prot_proj_bf, prot_mask, pw);

    pool_k<<<dim3(B_, 2, 3), 128, 0, stream>>>(comp_proj_bf, cw, cp, LC_, 256);
    pool_k<<<dim3(B_, 8, 3), 128, 0, stream>>>(prot_proj_bf, pw, pp, LP_, 512);

    // layer-2 contexts (grid z = batch; W = per-b M/N of layer 2)
    hgemm_hl_k<false, false, true, false><<<dim3(LC_ / 64, 2, B_), 256, 0, stream>>>(
        comp_bil_bf + (size_t)2 * B_ * LC_ * H_, Mbuf + (size_t)2 * B_ * HH_,
        nullptr, comp_mask, out_cc, LC_);
    hgemm_hl_k<false, false, true, false><<<dim3(LP_ / 64, 2, B_), 256, 0, stream>>>(
        prot_proj_bf + (size_t)2 * B_ * LP_ * H_, Nbuf + (size_t)2 * B_ * HH_,
        nullptr, prot_mask, out_pc, LP_);

    final2_k<<<dim3(B_, 6), 128, 0, stream>>>(cp, Wcomb_c, bcomb_c, out_cf);
    final2_k<<<dim3(B_, 6), 128, 0, stream>>>(pp, Wcomb_p, bcomb_p, out_pf);
}

// Round 7
// 232.537 us; speedup vs baseline: 3.0171x; 1.1759x over previous
//
#include <hip/hip_runtime.h>
#include <math.h>

#define B_ 16
#define LC_ 512
#define LP_ 4096
#define H_ 128
#define HH_ (H_*H_)

typedef unsigned long long u64t;
typedef unsigned short u16t;
typedef __attribute__((ext_vector_type(8))) short bf16x8;
typedef __attribute__((ext_vector_type(4))) float f32x4;

__device__ __forceinline__ u16t f2bf(float f) {
    union { float f; unsigned u; } v; v.f = f;
    unsigned r = (v.u + 0x7FFFu + ((v.u >> 16) & 1u)) >> 16;
    return (u16t)r;
}
__device__ __forceinline__ float bf2f(u16t s) {
    union { unsigned u; float f; } v; v.u = ((unsigned)s) << 16; return v.f;
}
__device__ __forceinline__ float bflo(unsigned u) {
    union { unsigned u; float f; } v; v.u = u << 16; return v.f;
}
__device__ __forceinline__ float bfhi(unsigned u) {
    union { unsigned u; float f; } v; v.u = u & 0xffff0000u; return v.f;
}
__device__ __forceinline__ float ftanh(float x) {
    x = fminf(15.f, fmaxf(-15.f, x));
    float t = __expf(2.f * x);
    return (t - 1.f) / (t + 1.f);
}
__device__ __forceinline__ bf16x8 ldfragS(const short* base, int r, int k, int stride) {
    const u64t* p = (const u64t*)(base + (size_t)r * stride + k);
    union { bf16x8 v; u64t q[2]; } u;
    u.q[0] = p[0]; u.q[1] = p[1];
    return u.v;
}

// fp32 W rows [64 k][128 n] -> transposed bf16 hi/lo tiles [64 n][68], cols ncol0..+63.
__device__ __forceinline__ void stage64_hl(const float* __restrict__ src, int ncol0,
                                           short* __restrict__ hi, short* __restrict__ lo,
                                           int t) {
    const int m = t & 15, kq = t >> 4;
    const int kc = kq * 4;
    float c[4][4];
#pragma unroll
    for (int r = 0; r < 4; ++r) {
        float4 v = *(const float4*)(src + (size_t)(kc + r) * H_ + ncol0 + m * 4);
        c[r][0] = v.x; c[r][1] = v.y; c[r][2] = v.z; c[r][3] = v.w;
    }
#pragma unroll
    for (int i = 0; i < 4; ++i) {
        u64t vh = 0, vl = 0;
#pragma unroll
        for (int r = 0; r < 4; ++r) {
            u16t h = f2bf(c[r][i]);
            u16t l2 = f2bf(c[r][i] - bf2f(h));
            vh |= (u64t)h << (16 * r);
            vl |= (u64t)l2 << (16 * r);
        }
        *(u64t*)(hi + (size_t)(4 * m + i) * 68 + kc) = vh;
        *(u64t*)(lo + (size_t)(4 * m + i) * 68 + kc) = vl;
    }
}

// bf16 src [64 k][128 h] (+ optional per-k mask) -> transposed [128 h][68] bf16 tile.
__device__ __forceinline__ void stage64_bf(const u16t* __restrict__ src,
                                           const int* __restrict__ maskrow,
                                           short* __restrict__ dst, int t) {
    const int m = t & 31, kq = t >> 5;
#pragma unroll
    for (int p = 0; p < 2; ++p) {
        const int kc = p * 32 + kq * 4;
        u64t q[4];
#pragma unroll
        for (int r = 0; r < 4; ++r) {
            u64t v = *(const u64t*)(src + (size_t)(kc + r) * H_ + m * 4);
            if (maskrow && !maskrow[kc + r]) v = 0;
            q[r] = v;
        }
#pragma unroll
        for (int i = 0; i < 4; ++i) {
            u64t val = ((q[0] >> (16 * i)) & 0xffffull)
                     | (((q[1] >> (16 * i)) & 0xffffull) << 16)
                     | (((q[2] >> (16 * i)) & 0xffffull) << 32)
                     | (((q[3] >> (16 * i)) & 0xffffull) << 48);
            *(u64t*)(dst + (size_t)(4 * m + i) * 68 + kc) = val;
        }
    }
}

// ---- unified MFMA GEMM: Y[wsel-unit row,:] = post( X @ W[wsel] + bias[wsel?] ) ----
template<bool TANH, bool BF16OUT, bool XPERW, bool BIASPERW>
__global__ __launch_bounds__(256) void hgemm_hl_k(const u16t* __restrict__ Xall,
                                                  const float* __restrict__ Wall,
                                                  const float* __restrict__ biasAll,
                                                  const int* __restrict__ mask,
                                                  void* __restrict__ Yout,
                                                  int rows) {
    __shared__ __align__(16) short Hi0[64 * 68], Hi1[64 * 68];
    __shared__ __align__(16) short Lo0[64 * 68], Lo1[64 * 68];
    __shared__ __align__(16) short Xs[64 * 136];
    const int t = threadIdx.x;
    const int wsel = blockIdx.z, nh = blockIdx.y;
    const long yrow0 = (long)wsel * rows + (long)blockIdx.x * 64;
    const u16t* X = XPERW ? (Xall + (size_t)yrow0 * H_)
                          : (Xall + (size_t)blockIdx.x * 64 * H_);
    const float* W = Wall + (size_t)wsel * HH_;

    stage64_hl(W, nh * 64, Hi0, Lo0, t);
    stage64_hl(W + 64 * H_, nh * 64, Hi1, Lo1, t);
    {
        const uint4* src = (const uint4*)X;
#pragma unroll
        for (int j = 0; j < 4; ++j) {
            int lin = j * 256 + t;
            *(uint4*)(Xs + (lin >> 4) * 136 + (lin & 15) * 8) = src[lin];
        }
    }
    __syncthreads();

    const int l = t & 63, w = t >> 6;
    const int lm = l & 15, lk = (l >> 4) * 8, lr = (l >> 4) * 4;
    const int cl = w * 16 + lm;
    f32x4 acc[4] = {};
#pragma unroll
    for (int ks = 0; ks < 128; ks += 32) {
        const short* Hi = (ks & 64) ? Hi1 : Hi0;
        const short* Lo = (ks & 64) ? Lo1 : Lo0;
        const int kk = ks & 32;
        bf16x8 bh = ldfragS(Hi, cl, kk + lk, 68);
        bf16x8 bl = ldfragS(Lo, cl, kk + lk, 68);
#pragma unroll
        for (int it = 0; it < 4; ++it) {
            bf16x8 af = ldfragS(Xs, it * 16 + lm, ks + lk, 136);
            acc[it] = __builtin_amdgcn_mfma_f32_16x16x32_bf16(af, bh, acc[it], 0, 0, 0);
            acc[it] = __builtin_amdgcn_mfma_f32_16x16x32_bf16(af, bl, acc[it], 0, 0, 0);
        }
    }

    const int colg = nh * 64 + w * 16 + lm;
    const float bv = biasAll ? biasAll[(BIASPERW ? wsel * H_ : 0) + colg] : 0.f;
#pragma unroll
    for (int it = 0; it < 4; ++it) {
#pragma unroll
        for (int r = 0; r < 4; ++r) {
            long row = yrow0 + it * 16 + lr + r;
            float v = acc[it][r] + bv;
            if (TANH) v = ftanh(v);
            if (mask) v *= (float)mask[row];
            if (BF16OUT) ((u16t*)Yout)[(size_t)row * H_ + colg] = f2bf(v);
            else ((float*)Yout)[(size_t)row * H_ + colg] = v;
        }
    }
}

// part[lay][slice][b] = sum over slice's k of (mask*Xl[lay,b,k,:])^T outer Yr[lay,b,k,:]
template<bool SAME>
__global__ __launch_bounds__(256) void syrk_mfma_k(const u16t* __restrict__ Xl,
                                                   const u16t* __restrict__ Yr,
                                                   const int* __restrict__ mask,
                                                   float* __restrict__ part,
                                                   int Kb, int rowsPerSlice, int slices) {
    extern __shared__ short smem[];
    short* Xt = smem;
    short* Yt = SAME ? smem : (smem + 128 * 68);
    const int t = threadIdx.x;
    const int b = blockIdx.y, slice = blockIdx.x, lay = blockIdx.z;
    const int l = t & 63, w = t >> 6;
    const int qi = (w >> 1) * 64, qj = (w & 1) * 64;
    const int lm = l & 15, lk = (l >> 4) * 8, lr = (l >> 4) * 4;

    f32x4 acc[4][4] = {};
    const int chunks = rowsPerSlice >> 6;
    const size_t doff = ((size_t)lay * B_ + b) * Kb;
    const size_t moff = (size_t)b * Kb;

    for (int c = 0; c < chunks; ++c) {
        const int kbase = slice * rowsPerSlice + c * 64;
        stage64_bf(Xl + (doff + kbase) * H_, mask + moff + kbase, Xt, t);
        if (!SAME) stage64_bf(Yr + (doff + kbase) * H_, nullptr, Yt, t);
        __syncthreads();
#pragma unroll
        for (int ks = 0; ks < 64; ks += 32) {
            bf16x8 af[4], bfr[4];
#pragma unroll
            for (int it = 0; it < 4; ++it) af[it] = ldfragS(Xt, qi + it * 16 + lm, ks + lk, 68);
#pragma unroll
            for (int jt = 0; jt < 4; ++jt) bfr[jt] = ldfragS(Yt, qj + jt * 16 + lm, ks + lk, 68);
#pragma unroll
            for (int it = 0; it < 4; ++it)
#pragma unroll
                for (int jt = 0; jt < 4; ++jt)
                    acc[it][jt] = __builtin_amdgcn_mfma_f32_16x16x32_bf16(
                        af[it], bfr[jt], acc[it][jt], 0, 0, 0);
        }
        __syncthreads();
    }

    float* pb = part + (((size_t)lay * slices + slice) * B_ + b) * HH_;
#pragma unroll
    for (int it = 0; it < 4; ++it)
#pragma unroll
        for (int jt = 0; jt < 4; ++jt)
#pragma unroll
            for (int r = 0; r < 4; ++r)
                pb[(size_t)(qi + it * 16 + lr + r) * H_ + qj + jt * 16 + lm] = acc[it][jt][r];
}

__global__ __launch_bounds__(256) void reduce_k(const float4* __restrict__ part,
                                                float4* __restrict__ out, int slices) {
    const int lay = blockIdx.y;
    const size_t idx = (size_t)blockIdx.x * 256 + threadIdx.x;
    const size_t quarter = (size_t)B_ * HH_ / 4;
    const float4* p = part + (size_t)lay * slices * quarter;
    float4 a = p[idx];
    for (int s = 1; s < slices; ++s) {
        float4 v = p[(size_t)s * quarter + idx];
        a.x += v.x; a.y += v.y; a.z += v.z; a.w += v.w;
    }
    (out + (size_t)lay * quarter)[idx] = a;
}

__global__ void tobf16_k(const float4* __restrict__ in, uint4* __restrict__ out) {
    int idx = blockIdx.x * 256 + threadIdx.x;
    float4 a = in[2 * idx], b = in[2 * idx + 1];
    uint4 o;
    o.x = (unsigned)f2bf(a.x) | ((unsigned)f2bf(a.y) << 16);
    o.y = (unsigned)f2bf(a.z) | ((unsigned)f2bf(a.w) << 16);
    o.z = (unsigned)f2bf(b.x) | ((unsigned)f2bf(b.y) << 16);
    o.w = (unsigned)f2bf(b.z) | ((unsigned)f2bf(b.w) << 16);
    out[idx] = o;
}

// ---- vc[lay,b] = M[lay,b] @ Wac[lay] ; vp[lay,b] = N[lay,b] @ Wap[lay] ----
__global__ void mv_k(const float* __restrict__ M, const float* __restrict__ N,
                     const float* __restrict__ WacAll, const float* __restrict__ WapAll,
                     float* __restrict__ vcAll, float* __restrict__ vpAll) {
    const int b = blockIdx.x, lay = blockIdx.y, t = threadIdx.x;
    const size_t mo = ((size_t)lay * B_ + b) * HH_;
    const float* mat = (t < 128) ? (M + mo + (size_t)t * H_) : (N + mo + (size_t)(t - 128) * H_);
    const float* w = (t < 128) ? (WacAll + lay * H_) : (WapAll + lay * H_);
    float acc = 0.f;
#pragma unroll 8
    for (int h = 0; h < H_; ++h) acc = fmaf(mat[h], w[h], acc);
    if (t < 128) vcAll[((size_t)lay * B_ + b) * H_ + t] = acc;
    else         vpAll[((size_t)lay * B_ + b) * H_ + (t - 128)] = acc;
}

// ---- logits[lay,b,r] = mask[b,r] * (feat[lay,b,r,:] . v[lay,b]) + bias[lay] ----
// grid: (N/256, B, 3), one thread per row.
template<int N>
__global__ __launch_bounds__(256) void logits2_k(const u16t* __restrict__ featAll,
                                                 const int* __restrict__ maskAll,
                                                 const float* __restrict__ vAll,
                                                 const float* __restrict__ bvAll,
                                                 float* __restrict__ out) {
    __shared__ float v[H_];
    const int b = blockIdx.y, lay = blockIdx.z, t = threadIdx.x;
    if (t < 128) v[t] = vAll[((size_t)lay * B_ + b) * H_ + t];
    __syncthreads();
    const int r = blockIdx.x * 256 + t;
    const uint2* f2 = (const uint2*)(featAll + (((size_t)lay * B_ + b) * (size_t)N + r) * H_);
    const float4* v4 = (const float4*)v;
    float acc = 0.f;
#pragma unroll
    for (int h4 = 0; h4 < 32; ++h4) {
        uint2 u = f2[h4];
        float4 c = v4[h4];
        acc = fmaf(bflo(u.x), c.x, acc); acc = fmaf(bfhi(u.x), c.y, acc);
        acc = fmaf(bflo(u.y), c.z, acc); acc = fmaf(bfhi(u.y), c.w, acc);
    }
    out[((size_t)lay * B_ + b) * N + r] = (float)maskAll[(size_t)b * N + r] * acc + bvAll[lay];
}

// ---- masked softmax, faithful: max over ALL, exp*mask, denom + 1e-6 ----
template<int N>
__global__ __launch_bounds__(256) void softmax_k(const float* __restrict__ logits,
                                                 const int* __restrict__ mask,
                                                 float* __restrict__ w) {
    const int b = blockIdx.x, lay = blockIdx.y, t = threadIdx.x;
    const float* l = logits + ((size_t)lay * B_ + b) * N;
    const int* mk = mask + (size_t)b * N;
    float* ww = w + ((size_t)lay * B_ + b) * N;
    __shared__ float Es[N];
    __shared__ float red[4];

    float mx = -1e30f;
    for (int q = t; q < N; q += 256) { float x = l[q]; Es[q] = x; mx = fmaxf(mx, x); }
#pragma unroll
    for (int o = 32; o > 0; o >>= 1) mx = fmaxf(mx, __shfl_down(mx, o, 64));
    if ((t & 63) == 0) red[t >> 6] = mx;
    __syncthreads();
    float m = fmaxf(fmaxf(red[0], red[1]), fmaxf(red[2], red[3]));
    __syncthreads();

    float s = 0.f;
    for (int q = t; q < N; q += 256) {
        float e = __expf(Es[q] - m) * (float)mk[q];
        Es[q] = e;
        s += e;
    }
#pragma unroll
    for (int o = 32; o > 0; o >>= 1) s += __shfl_down(s, o, 64);
    if ((t & 63) == 0) red[t >> 6] = s;
    __syncthreads();
    float denom = red[0] + red[1] + red[2] + red[3] + 1e-6f;
    for (int q = t; q < N; q += 256) ww[q] = Es[q] / denom;
}

// ---- pooled[lay,b,h] += sum_{q in chunk} proj_bf16[lay,b,q,h] * w[lay,b,q] ----
// 256 threads: th = t&63 -> h-pair (2*th, 2*th+1); tq = t>>6 -> 4 rows in flight.
__global__ __launch_bounds__(256) void pool_k(const u16t* __restrict__ proj,
                                              const float* __restrict__ w,
                                              float* __restrict__ out, int n, int chunk) {
    const int b = blockIdx.x, lay = blockIdx.z, t = threadIdx.x;
    const int th = t & 63, tq = t >> 6;
    const int q0 = blockIdx.y * chunk;
    const u16t* pb = proj + (((size_t)lay * B_ + b) * n + q0) * H_;
    const float* wb = w + ((size_t)lay * B_ + b) * n + q0;
    float a0 = 0.f, a1 = 0.f;
    for (int q = tq; q < chunk; q += 4) {
        float wq = wb[q];
        unsigned u = *(const unsigned*)(pb + (size_t)q * H_ + th * 2);
        a0 = fmaf(bflo(u), wq, a0);
        a1 = fmaf(bfhi(u), wq, a1);
    }
    float* ob = out + ((size_t)lay * B_ + b) * H_;
    atomicAdd(&ob[th * 2], a0);
    atomicAdd(&ob[th * 2 + 1], a1);
}

// ---- final[b,h] += sum_{j in chunk} pooled[j>>7, b, j&127] * Wcomb[j,h] (+bias) ----
__global__ void final2_k(const float* __restrict__ pooled, const float* __restrict__ Wcomb,
                         const float* __restrict__ bcomb, float* __restrict__ out) {
    const int b = blockIdx.x, h = threadIdx.x, j0 = blockIdx.y * 64;
    float acc = (blockIdx.y == 0) ? bcomb[h] : 0.f;
#pragma unroll 4
    for (int j = 0; j < 64; ++j) {
        int jj = j0 + j;
        int lay = jj >> 7, hh = jj & 127;
        acc = fmaf(pooled[((size_t)lay * B_ + b) * H_ + hh], Wcomb[(size_t)jj * H_ + h], acc);
    }
    atomicAdd(&out[b * H_ + h], acc);
}

extern "C" void kernel_launch(void* const* d_in, const int* in_sizes, int n_in,
                              void* d_out, int out_size, void* d_ws, size_t ws_size,
                              hipStream_t stream) {
    const float* comp_feat = (const float*)d_in[0];
    const int*   comp_mask = (const int*)d_in[1];
    const float* prot_feat = (const float*)d_in[2];
    const int*   prot_mask = (const int*)d_in[3];
    const float* Wc      = (const float*)d_in[4];
    const float* bc      = (const float*)d_in[5];
    const float* Wp      = (const float*)d_in[6];
    const float* bp      = (const float*)d_in[7];
    const float* Wbl     = (const float*)d_in[8];
    const float* Wac     = (const float*)d_in[9];
    const float* bac     = (const float*)d_in[10];
    const float* Wap     = (const float*)d_in[11];
    const float* bap     = (const float*)d_in[12];
    const float* Wcomb_c = (const float*)d_in[13];
    const float* bcomb_c = (const float*)d_in[14];
    const float* Wcomb_p = (const float*)d_in[15];
    const float* bcomb_p = (const float*)d_in[16];

    // ---- workspace: bf16 region, then fp32 region (~115 MB total) ----
    u16t* prot_feat_bf = (u16t*)d_ws;                                    // B*LP*H
    u16t* comp_feat_bf = prot_feat_bf + (size_t)B_ * LP_ * H_;           // B*LC*H
    u16t* prot_proj_bf = comp_feat_bf + (size_t)B_ * LC_ * H_;           // 3*B*LP*H
    u16t* comp_proj_bf = prot_proj_bf + (size_t)3 * B_ * LP_ * H_;       // 3*B*LC*H
    u16t* comp_bil_bf  = comp_proj_bf + (size_t)3 * B_ * LC_ * H_;       // 3*B*LC*H
    float* f = (float*)(comp_bil_bf + (size_t)3 * B_ * LC_ * H_);
    float* Mbuf = f; f += (size_t)3 * B_ * HH_;
    float* Nbuf = f; f += (size_t)3 * B_ * HH_;
    float* vc = f;   f += (size_t)3 * B_ * H_;
    float* vp = f;   f += (size_t)3 * B_ * H_;
    float* logc = f; f += (size_t)3 * B_ * LC_;
    float* logp = f; f += (size_t)3 * B_ * LP_;
    float* cw = f;   f += (size_t)3 * B_ * LC_;
    float* pw = f;   f += (size_t)3 * B_ * LP_;
    float* cp = f;   f += 3 * B_ * H_;
    float* pp = f;   f += 3 * B_ * H_;
    float* part = f; // 3 * 8 * B * HH floats = 25.2 MB

    float* out_cf = (float*)d_out;
    float* out_pf = out_cf + B_ * H_;
    float* out_cc = out_pf + B_ * H_;
    float* out_pc = out_cc + (size_t)B_ * LC_ * H_;

    const int SL = 8;

    tobf16_k<<<dim3(B_ * LP_ * H_ / 8 / 256), 256, 0, stream>>>(
        (const float4*)prot_feat, (uint4*)prot_feat_bf);
    tobf16_k<<<dim3(B_ * LC_ * H_ / 8 / 256), 256, 0, stream>>>(
        (const float4*)comp_feat, (uint4*)comp_feat_bf);
    hipMemsetAsync(cp, 0, (size_t)2 * 3 * B_ * H_ * sizeof(float), stream);
    hipMemsetAsync(d_out, 0, (size_t)2 * B_ * H_ * sizeof(float), stream);

    // projections (all 3 layers batched in grid z)
    hgemm_hl_k<true, true, false, true><<<dim3(B_ * LP_ / 64, 2, 3), 256, 0, stream>>>(
        prot_feat_bf, Wp, bp, nullptr, prot_proj_bf, B_ * LP_);
    hgemm_hl_k<true, true, false, true><<<dim3(B_ * LC_ / 64, 2, 3), 256, 0, stream>>>(
        comp_feat_bf, Wc, bc, nullptr, comp_proj_bf, B_ * LC_);
    hgemm_hl_k<false, true, true, false><<<dim3(B_ * LC_ / 64, 2, 3), 256, 0, stream>>>(
        comp_proj_bf, Wbl, nullptr, nullptr, comp_bil_bf, B_ * LC_);

    // M[lay] = P^T diag(pm) P ; N[lay] = Bil^T diag(cm) Cproj
    syrk_mfma_k<true><<<dim3(SL, B_, 3), 256, 128 * 68 * sizeof(short), stream>>>(
        prot_proj_bf, prot_proj_bf, prot_mask, part, LP_, LP_ / SL, SL);
    reduce_k<<<dim3(B_ * HH_ / 4 / 256, 3), 256, 0, stream>>>(
        (const float4*)part, (float4*)Mbuf, SL);
    syrk_mfma_k<false><<<dim3(SL, B_, 3), 256, 2 * 128 * 68 * sizeof(short), stream>>>(
        comp_bil_bf, comp_proj_bf, comp_mask, part, LC_, LC_ / SL, SL);
    reduce_k<<<dim3(B_ * HH_ / 4 / 256, 3), 256, 0, stream>>>(
        (const float4*)part, (float4*)Nbuf, SL);

    // v, logits (one thread per row), masked softmax
    mv_k<<<dim3(B_, 3), 256, 0, stream>>>(Mbuf, Nbuf, Wac, Wap, vc, vp);
    logits2_k<LC_><<<dim3(LC_ / 256, B_, 3), 256, 0, stream>>>(
        comp_bil_bf, comp_mask, vc, bac, logc);
    logits2_k<LP_><<<dim3(LP_ / 256, B_, 3), 256, 0, stream>>>(
        prot_proj_bf, prot_mask, vp, bap, logp);
    softmax_k<LC_><<<dim3(B_, 3), 256, 0, stream>>>(logc, comp_mask, cw);
    softmax_k<LP_><<<dim3(B_, 3), 256, 0, stream>>>(logp, prot_mask, pw);

    pool_k<<<dim3(B_, 4, 3), 256, 0, stream>>>(comp_proj_bf, cw, cp, LC_, 128);
    pool_k<<<dim3(B_, 16, 3), 256, 0, stream>>>(prot_proj_bf, pw, pp, LP_, 256);

    // layer-2 contexts (grid z = batch; W = per-b M/N of layer 2)
    hgemm_hl_k<false, false, true, false><<<dim3(LC_ / 64, 2, B_), 256, 0, stream>>>(
        comp_bil_bf + (size_t)2 * B_ * LC_ * H_, Mbuf + (size_t)2 * B_ * HH_,
        nullptr, comp_mask, out_cc, LC_);
    hgemm_hl_k<false, false, true, false><<<dim3(LP_ / 64, 2, B_), 256, 0, stream>>>(
        prot_proj_bf + (size_t)2 * B_ * LP_ * H_, Nbuf + (size_t)2 * B_ * HH_,
        nullptr, prot_mask, out_pc, LP_);

    final2_k<<<dim3(B_, 6), 128, 0, stream>>>(cp, Wcomb_c, bcomb_c, out_cf);
    final2_k<<<dim3(B_, 6), 128, 0, stream>>>(pp, Wcomb_p, bcomb_p, out_pf);
}